// Round 11
// baseline (643.006 us; speedup 1.0000x reference)
//
#include <hip/hip_runtime.h>

#define NN 20000
#define NE 640000
#define HD 128
#define NL 3
#define NG 128
#define NC 2
#define BN_EPS 1e-5f
#define NR 4            // stat replicas (atomic spread)
#define AST 136
#define NB 157          // dst buckets (dst >> 7), 128 nodes each
#define BCAP 6144       // records per bucket (mean 4076, +32 sigma)
#define AG1B 1250       // ag1 grid (16-node tiles); <= 1280 co-resident capacity

// Determinism scales. All cross-thread accumulation is either integer-exact
// or grid-quantized-exact float, so every call is bit-identical:
//  - WGRID (1/256): per-node BN-ReLU outputs quantized to the 2^-8 grid
//    (phase 0 of k_ag1) and stored as fp16 (every multiple of 2^-8 below 8.0
//    is fp16-exact; >=8 rounds to a coarser fp16 grid, still a 2^-8 multiple).
//    Aggregation sums of grid terms in f32 stay exact (|sum|*256 < 2^24)
//    => order-free AND partition-free (used by the half-list split).
//    This also makes csr_src ordering irrelevant to the output bits.
//  - SXS: layer-0 x sums in int32 (|x|<=5, deg<=70 -> < 2^31).
//  - STS/SCS: BN stats / layer-0 scalar moments in int64 fixed point.
#define WGRID 256.0f
#define SXS 65536.0f
#define STS 262144.0
#define SCS 1048576.0

typedef __attribute__((ext_vector_type(4))) float f32x4;
typedef __attribute__((ext_vector_type(8))) _Float16 f16x8;
typedef long long i64;

__device__ inline void stat_add(i64* p, float v) {
    atomicAdd((unsigned long long*)p, (unsigned long long)(i64)((double)v * STS));
}

// ---------- fused setup: weight fp16-split prep + p/q + edge bucketize ----------
// Bucketize stages records in LDS sorted by bucket, then streams them out:
// consecutive lanes write consecutive records whose destinations form
// contiguous runs per bucket -> ~8x fewer write transactions. [r9: +5 us]
__global__ void k_setup(const float* __restrict__ encW, const float* __restrict__ encb,
                        const float* __restrict__ W1, const float* __restrict__ W2,
                        const int* __restrict__ ei,
                        _Float16* __restrict__ Wt, float* __restrict__ pq,
                        int2* __restrict__ brec, int* __restrict__ gcur) {
    __shared__ int cnt[NB];
    __shared__ int base[NB];
    int b = blockIdx.x, tid = threadIdx.x;
    if (b < 48) {
        int t = b * 256 + tid;                 // 6*2048 = 12288
        if (t >= 6 * 2048) return;
        int mat = t >> 11;
        int rem = t & 2047;
        int n  = rem >> 4;
        int k0 = (rem & 15) * 8;
        int l  = mat >> 1;
        const float* src = (mat & 1) ? (W2 + l * HD * HD) : (W1 + l * HD * HD);
        _Float16* dhi = Wt + mat * HD * HD;
        _Float16* dlo = Wt + (6 + mat) * HD * HD;
        f16x8 hi, lo;
#pragma unroll
        for (int j = 0; j < 8; j++) {
            float w = src[(k0 + j) * HD + n];
            _Float16 hh = (_Float16)w;
            hi[j] = hh;
            lo[j] = (_Float16)((w - (float)hh) * 1024.0f);
        }
        *(f16x8*)&dhi[n * HD + k0] = hi;
        *(f16x8*)&dlo[n * HD + k0] = lo;
    } else if (b == 48) {
        if (tid < HD) {
            float ps = 0.f, qs = 0.f;
            for (int k = 0; k < HD; k++) {
                float w = W1[k * HD + tid];
                ps = fmaf(encW[k], w, ps);
                qs = fmaf(encb[k], w, qs);
            }
            pq[tid] = ps;
            pq[HD + tid] = qs;
        }
    } else {
        __shared__ int lscan[NB];              // inclusive local prefix
        __shared__ int cnt2[NB];
        __shared__ int2 st[1280];              // bucket-sorted staging
        int bb = b - 49;                       // 0..499, 1280 edges each (exact)
        for (int i = tid; i < NB; i += 256) { cnt[i] = 0; cnt2[i] = 0; }
        __syncthreads();
        int src[5], dst[5];
#pragma unroll
        for (int j = 0; j < 5; j++) {
            int e = bb * 1280 + j * 256 + tid;
            src[j] = ei[e];
            dst[j] = ei[NE + e];
            atomicAdd(&cnt[dst[j] >> 7], 1);
        }
        __syncthreads();
        // inclusive Hillis-Steele scan of cnt into lscan (NB <= 256)
        if (tid < NB) lscan[tid] = cnt[tid];
        __syncthreads();
        for (int off = 1; off < NB; off <<= 1) {
            int t = (tid < NB && tid >= off) ? lscan[tid - off] : 0;
            __syncthreads();
            if (tid < NB) lscan[tid] += t;
            __syncthreads();
        }
        // global reserve per bucket
        for (int i = tid; i < NB; i += 256)
            base[i] = atomicAdd(&gcur[i], cnt[i]);
        __syncthreads();
        // stage records sorted by bucket
#pragma unroll
        for (int j = 0; j < 5; j++) {
            int bk = dst[j] >> 7;
            int lpos = (lscan[bk] - cnt[bk]) + atomicAdd(&cnt2[bk], 1);
            st[lpos] = make_int2(src[j], dst[j]);
        }
        __syncthreads();
        // coalesced-run write-out
        for (int i = tid; i < 1280; i += 256) {
            int2 rc = st[i];
            int bk = rc.y >> 7;
            int excl = lscan[bk] - cnt[bk];
            brec[bk * BCAP + base[bk] + (i - excl)] = rc;
        }
    }
}

// ---------- CSR finalize + layer-0 scalar aggregation, per bucket ----------
// Single global pass; node-sorted in LDS; coalesced csr_src write-out.
__global__ void k_csr(const int2* __restrict__ brec, const int* __restrict__ gcur,
                      const float* __restrict__ x, const float* __restrict__ eps_gin,
                      int* __restrict__ row_ptr, int* __restrict__ csr_src,
                      float* __restrict__ av, float* __restrict__ dv,
                      i64* __restrict__ scal) {
    __shared__ int lc[128];
    __shared__ int sxi[128];
    __shared__ int pfx[128];
    __shared__ int sbase[4];
    __shared__ int cnt2[128];
    __shared__ int2 st[BCAP];                  // raw record staging (48 KB)
    __shared__ int  srt[BCAP];                 // node-sorted src ids (24 KB)
    int b = blockIdx.x, tid = threadIdx.x;
    if (tid < 128) { lc[tid] = 0; sxi[tid] = 0; cnt2[tid] = 0; }
    __syncthreads();
    int nrec = gcur[b];
    const int2* rec = brec + b * BCAP;
    // pass A: global->LDS copy + count + x-sum (int atomics, exact)
    for (int r = tid; r < nrec; r += 256) {
        int2 rc = rec[r];
        st[r] = rc;
        atomicAdd(&lc[rc.y & 127], 1);
        atomicAdd(&sxi[rc.y & 127], (int)rintf(x[rc.x] * SXS));
    }
    int v = (tid < b) ? gcur[tid] : 0;     // b <= 156 < 256
    v += __shfl_xor(v, 1);  v += __shfl_xor(v, 2);  v += __shfl_xor(v, 4);
    v += __shfl_xor(v, 8);  v += __shfl_xor(v, 16); v += __shfl_xor(v, 32);
    if ((tid & 63) == 0) sbase[tid >> 6] = v;
    __syncthreads();
    int base0 = sbase[0] + sbase[1] + sbase[2] + sbase[3];
    if (tid < 128) pfx[tid] = lc[tid];
    __syncthreads();
    for (int off = 1; off < 128; off <<= 1) {
        int t = (tid < 128 && tid >= off) ? pfx[tid - off] : 0;
        __syncthreads();
        if (tid < 128) pfx[tid] += t;
        __syncthreads();
    }
    if (tid < 128) {
        int node = b * 128 + tid;
        int e = base0 + pfx[tid] - lc[tid];   // exclusive
        if (node < NN) row_ptr[node] = e;
    }
    if (b == NB - 1 && tid == 0) row_ptr[NN] = NE;
    __syncthreads();
    // pass B: node-sort src ids (LDS -> LDS)
    for (int r = tid; r < nrec; r += 256) {
        int2 rc = st[r];
        int node = rc.y & 127;
        int lpos = (pfx[node] - lc[node]) + atomicAdd(&cnt2[node], 1);
        srt[lpos] = rc.x;
    }
    __syncthreads();
    // pass C: coalesced csr_src write-out
    for (int i = tid; i < nrec; i += 256)
        csr_src[base0 + i] = srt[i];
    __syncthreads();
    float a = 0.f, d = 0.f;
    if (tid < 128) {
        int node = b * 128 + tid;
        if (node < NN) {
            float e = 1.0f + eps_gin[0];
            float sxf = (float)sxi[tid] * (1.0f / SXS);
            a = fmaf(e, x[node], sxf);
            d = e + (float)lc[tid];
            av[node] = a;
            dv[node] = d;
        }
    }
    float vv[5] = { a, d, a * a, d * d, a * d };
#pragma unroll
    for (int j = 0; j < 5; j++) {
        float t = vv[j];
        t += __shfl_xor(t, 1);  t += __shfl_xor(t, 2);  t += __shfl_xor(t, 4);
        t += __shfl_xor(t, 8);  t += __shfl_xor(t, 16); t += __shfl_xor(t, 32);
        vv[j] = t;
    }
    if ((tid & 63) == 0 && tid < 128)
#pragma unroll
        for (int j = 0; j < 5; j++)
            atomicAdd((unsigned long long*)&scal[j],
                      (unsigned long long)(i64)((double)vv[j] * SCS));
}

// ---------- layer-0 GEMM2: rank-2 A, analytic BN, 3-term split, 32-row tile ----------
__global__ __launch_bounds__(256) void k_gemmA(
    const float* __restrict__ av, const float* __restrict__ dv,
    const float* __restrict__ pq, const i64* __restrict__ scal,
    const float* __restrict__ gamma, const float* __restrict__ beta,
    const _Float16* __restrict__ Whi, const _Float16* __restrict__ Wlo,
    _Float16* __restrict__ out0, _Float16* __restrict__ out1,
    i64* __restrict__ stat_out) {
    __shared__ __align__(16) _Float16 AsH[32 * AST];
    __shared__ __align__(16) _Float16 AsL[32 * AST];
    int tid  = threadIdx.x;
    int wave = tid >> 6, lane = tid & 63;
    int quad = lane >> 4, l16 = lane & 15;
    int r0   = blockIdx.x * 32;               // 625 blocks, no guards
    int n0w  = wave * 32;
    int rep  = (blockIdx.x & (NR - 1)) * 256;

    f16x8 bhi[2][4], blo[2][4];
#pragma unroll
    for (int nt = 0; nt < 2; nt++) {
        int n = n0w + nt * 16 + l16;
#pragma unroll
        for (int kq = 0; kq < 4; kq++) {
            int k = kq * 32 + quad * 8;
            bhi[nt][kq] = *(const f16x8*)&Whi[n * HD + k];
            blo[nt][kq] = *(const f16x8*)&Wlo[n * HD + k];
        }
    }

    {
        int c8 = (tid & 15) * 8;
        int nl = tid >> 4;
        float Sa  = (float)((double)scal[0] * (1.0 / SCS));
        float Sd  = (float)((double)scal[1] * (1.0 / SCS));
        float Saa = (float)((double)scal[2] * (1.0 / SCS));
        float Sdd = (float)((double)scal[3] * (1.0 / SCS));
        float Sad = (float)((double)scal[4] * (1.0 / SCS));
        float pj[8], qj[8], sc[8], sh[8];
#pragma unroll
        for (int j = 0; j < 8; j++) {
            float P = pq[c8 + j], Q = pq[HD + c8 + j];
            pj[j] = P; qj[j] = Q;
            float mu  = (Sa * P + Sd * Q) * (1.0f / NN);
            float ex2 = (Saa * P * P + 2.f * Sad * P * Q + Sdd * Q * Q) * (1.0f / NN);
            float var = ex2 - mu * mu;
            float g = gamma[c8 + j] * rsqrtf(var + BN_EPS);
            sc[j] = g;
            sh[j] = beta[c8 + j] - g * mu;
        }
#pragma unroll
        for (int i = 0; i < 2; i++) {
            int r = i * 16 + nl;
            int row = r0 + r;
            float a = av[row], d = dv[row];
            f16x8 hh, ll;
#pragma unroll
            for (int j = 0; j < 8; j++) {
                float t0 = fmaf(a, pj[j], d * qj[j]);
                float v = fmaxf(fmaf(sc[j], t0, sh[j]), 0.f);
                _Float16 h = (_Float16)v;
                hh[j] = h;
                ll[j] = (_Float16)((v - (float)h) * 512.0f);
            }
            *(f16x8*)&AsH[r * AST + c8] = hh;
            *(f16x8*)&AsL[r * AST + c8] = ll;
        }
    }
    __syncthreads();

    f32x4 ahh[2][2], ahl[2][2], alh[2][2];
#pragma unroll
    for (int mt = 0; mt < 2; mt++)
#pragma unroll
        for (int nt = 0; nt < 2; nt++)
#pragma unroll
            for (int e2 = 0; e2 < 4; e2++) {
                ahh[mt][nt][e2] = 0.f; ahl[mt][nt][e2] = 0.f; alh[mt][nt][e2] = 0.f;
            }

#pragma unroll
    for (int mt = 0; mt < 2; mt++) {
        int mrow = mt * 16 + l16;
#pragma unroll
        for (int kq = 0; kq < 4; kq++) {
            f16x8 ah = *(const f16x8*)&AsH[mrow * AST + kq * 32 + quad * 8];
            f16x8 al = *(const f16x8*)&AsL[mrow * AST + kq * 32 + quad * 8];
#pragma unroll
            for (int nt = 0; nt < 2; nt++) {
                ahh[mt][nt] = __builtin_amdgcn_mfma_f32_16x16x32_f16(ah, bhi[nt][kq], ahh[mt][nt], 0, 0, 0);
                ahl[mt][nt] = __builtin_amdgcn_mfma_f32_16x16x32_f16(ah, blo[nt][kq], ahl[mt][nt], 0, 0, 0);
                alh[mt][nt] = __builtin_amdgcn_mfma_f32_16x16x32_f16(al, bhi[nt][kq], alh[mt][nt], 0, 0, 0);
            }
        }
    }

    float s[2] = { 0.f, 0.f }, q[2] = { 0.f, 0.f };
#pragma unroll
    for (int mt = 0; mt < 2; mt++) {
        int rbase = r0 + mt * 16 + quad * 4;
#pragma unroll
        for (int rr = 0; rr < 4; rr++) {
            int row = rbase + rr;
#pragma unroll
            for (int nt = 0; nt < 2; nt++) {
                float v = ahh[mt][nt][rr] + ahl[mt][nt][rr] * (1.0f / 1024.0f)
                        + alh[mt][nt][rr] * (1.0f / 512.0f);
                int col = n0w + nt * 16 + l16;
                _Float16* dst = (col < 64) ? out0 : out1;
                dst[row * 64 + (col & 63)] = (_Float16)v;
                s[nt] += v;
                q[nt] = fmaf(v, v, q[nt]);
            }
        }
    }
#pragma unroll
    for (int nt = 0; nt < 2; nt++) {
        float ss = s[nt], qq = q[nt];
        ss += __shfl_xor(ss, 16); ss += __shfl_xor(ss, 32);
        qq += __shfl_xor(qq, 16); qq += __shfl_xor(qq, 32);
        if (lane < 16) {
            stat_add(&stat_out[rep + n0w + nt * 16 + lane], ss);
            stat_add(&stat_out[rep + 128 + n0w + nt * 16 + lane], qq);
        }
    }
}

// ---------- FUSED vq + aggregation + GEMM1, 16-row tile, 256 threads ----------
// Phase 0 (was k_vq): this block quantizes ITS OWN 16 nodes' BN-ReLU outputs
// to the 2^-8 grid in fp16 (wq). Then a device-wide spin barrier (release
// atomicAdd + acquire spin; __threadfence flushes dirty L2 to L3 for
// cross-XCD visibility), then the unchanged gather+MFMA body.
// DEADLOCK-FREE: __launch_bounds__(256,5) guarantees 5 blocks/CU
// (VGPR<=102, LDS 9.7KB) -> capacity 1280 >= grid 1250, all co-resident.
__global__ __launch_bounds__(256, 5) void k_ag1(
    const int* __restrict__ row_ptr, const int* __restrict__ csr_src,
    const _Float16* __restrict__ u0, const _Float16* __restrict__ u1,
    const i64* __restrict__ stat_in,
    const float* __restrict__ gamma, const float* __restrict__ beta,
    const float* __restrict__ eps_gin, int l,
    const _Float16* __restrict__ Whi, const _Float16* __restrict__ Wlo,
    _Float16* __restrict__ wq,
    float* __restrict__ outT, i64* __restrict__ stat_out,
    int* __restrict__ bar) {
    __shared__ __align__(16) _Float16 AsH[16 * AST];
    __shared__ __align__(16) _Float16 AsL[16 * AST];
    __shared__ float scs[HD], shs[HD];
    int tid  = threadIdx.x;
    int wave = tid >> 6, lane = tid & 63;
    int quad = lane >> 4, l16 = lane & 15;
    int r0   = blockIdx.x * 16;               // 1250 blocks, no guards
    int n0w  = wave * 32;
    int rep  = (blockIdx.x & (NR - 1)) * 256;

    // ---- phase 0: per-node BN+ReLU+quantize for this block's 16 nodes ----
    if (tid < HD) {
        i64 S = 0, Q = 0;
#pragma unroll
        for (int r = 0; r < NR; r++) {
            S += stat_in[r * 256 + tid];
            Q += stat_in[r * 256 + 128 + tid];
        }
        float ssum = (float)((double)S * (1.0 / STS));
        float ssq  = (float)((double)Q * (1.0 / STS));
        float mu  = ssum * (1.0f / NN);
        float var = ssq * (1.0f / NN) - mu * mu;
        float a = gamma[tid] * rsqrtf(var + BN_EPS);
        scs[tid] = a * WGRID;
        shs[tid] = (beta[tid] - a * mu) * WGRID;
    }
    __syncthreads();
    {
        int n = r0 + (tid >> 4);
        int sub = tid & 15;
        int half = sub >> 3;
        int c8in = (sub & 7) * 8;
        int c8 = half * 64 + c8in;
        const _Float16* u = half ? u1 : u0;
        f16x8 rv = *(const f16x8*)&u[n * 64 + c8in];
        f16x8 o;
#pragma unroll
        for (int j = 0; j < 8; j++)
            o[j] = (_Float16)(rintf(fmaxf(fmaf(scs[c8 + j], (float)rv[j], shs[c8 + j]), 0.f))
                              * (1.0f / WGRID));
        *(f16x8*)&wq[n * HD + c8] = o;
    }
    // ---- device-wide barrier: all wq writes visible before any gather ----
    __threadfence();                           // flush dirty L2 -> L3 (agent)
    __syncthreads();
    if (tid == 0) {
        __hip_atomic_fetch_add(bar, 1, __ATOMIC_RELEASE, __HIP_MEMORY_SCOPE_AGENT);
        while (__hip_atomic_load(bar, __ATOMIC_ACQUIRE, __HIP_MEMORY_SCOPE_AGENT) < AG1B)
            __builtin_amdgcn_s_sleep(2);
    }
    __syncthreads();

    // ---- phase 1: aggregation (half-list split) ----
    float e = 1.0f + eps_gin[l];
    {
        int node = tid >> 4;                  // 0..15
        int sub  = tid & 15;
        int hl   = sub >> 3;                  // which half of the edge list
        int c0   = (sub & 7) * 16;            // 16-channel base
        int n = r0 + node;
        int p0 = row_ptr[n], end0 = row_ptr[n + 1];
        int mid = p0 + ((end0 - p0) >> 1);
        float acc[16];
        if (hl == 0) {
            f16x8 s0 = *(const f16x8*)&wq[n * HD + c0];
            f16x8 s1 = *(const f16x8*)&wq[n * HD + c0 + 8];
#pragma unroll
            for (int j = 0; j < 8; j++) {
                acc[j]     = rintf(e * (float)s0[j] * WGRID) * (1.0f / WGRID);
                acc[8 + j] = rintf(e * (float)s1[j] * WGRID) * (1.0f / WGRID);
            }
        } else {
#pragma unroll
            for (int j = 0; j < 16; j++) acc[j] = 0.f;
        }
        int p   = hl ? mid : p0;
        int end = hl ? end0 : mid;
        for (; p + 3 < end; p += 4) {
            f16x8 ra[4], rb[4];
#pragma unroll
            for (int k = 0; k < 4; k++) {
                int s = csr_src[p + k];
                ra[k] = *(const f16x8*)&wq[s * HD + c0];
                rb[k] = *(const f16x8*)&wq[s * HD + c0 + 8];
            }
#pragma unroll
            for (int k = 0; k < 4; k++)
#pragma unroll
                for (int j = 0; j < 8; j++) {
                    acc[j]     += (float)ra[k][j];
                    acc[8 + j] += (float)rb[k][j];
                }
        }
        for (; p < end; p++) {
            int s = csr_src[p];
            f16x8 r0v = *(const f16x8*)&wq[s * HD + c0];
            f16x8 r1v = *(const f16x8*)&wq[s * HD + c0 + 8];
#pragma unroll
            for (int j = 0; j < 8; j++) {
                acc[j]     += (float)r0v[j];
                acc[8 + j] += (float)r1v[j];
            }
        }
        // combine the two half-list partials (exact grid -> order-free)
#pragma unroll
        for (int j = 0; j < 16; j++) acc[j] += __shfl_xor(acc[j], 8);
        if (hl == 0) {
            f16x8 hh0, ll0, hh1, ll1;
#pragma unroll
            for (int j = 0; j < 8; j++) {
                float v0 = acc[j];
                _Float16 h0 = (_Float16)v0;
                hh0[j] = h0;
                ll0[j] = (_Float16)((v0 - (float)h0) * 512.0f);
                float v1 = acc[8 + j];
                _Float16 h1 = (_Float16)v1;
                hh1[j] = h1;
                ll1[j] = (_Float16)((v1 - (float)h1) * 512.0f);
            }
            *(f16x8*)&AsH[node * AST + c0]     = hh0;
            *(f16x8*)&AsH[node * AST + c0 + 8] = hh1;
            *(f16x8*)&AsL[node * AST + c0]     = ll0;
            *(f16x8*)&AsL[node * AST + c0 + 8] = ll1;
        }
    }

    f16x8 bhi[2][4], blo[2][4];
#pragma unroll
    for (int nt = 0; nt < 2; nt++) {
        int n = n0w + nt * 16 + l16;
#pragma unroll
        for (int kq = 0; kq < 4; kq++) {
            int k = kq * 32 + quad * 8;
            bhi[nt][kq] = *(const f16x8*)&Whi[n * HD + k];
            blo[nt][kq] = *(const f16x8*)&Wlo[n * HD + k];
        }
    }
    __syncthreads();

    f32x4 ahh[2], ahl[2], alh[2];
#pragma unroll
    for (int nt = 0; nt < 2; nt++)
#pragma unroll
        for (int e2 = 0; e2 < 4; e2++) {
            ahh[nt][e2] = 0.f; ahl[nt][e2] = 0.f; alh[nt][e2] = 0.f;
        }

#pragma unroll
    for (int kq = 0; kq < 4; kq++) {
        f16x8 ah = *(const f16x8*)&AsH[l16 * AST + kq * 32 + quad * 8];
        f16x8 al = *(const f16x8*)&AsL[l16 * AST + kq * 32 + quad * 8];
#pragma unroll
        for (int nt = 0; nt < 2; nt++) {
            ahh[nt] = __builtin_amdgcn_mfma_f32_16x16x32_f16(ah, bhi[nt][kq], ahh[nt], 0, 0, 0);
            ahl[nt] = __builtin_amdgcn_mfma_f32_16x16x32_f16(ah, blo[nt][kq], ahl[nt], 0, 0, 0);
            alh[nt] = __builtin_amdgcn_mfma_f32_16x16x32_f16(al, bhi[nt][kq], alh[nt], 0, 0, 0);
        }
    }

    float s[2] = { 0.f, 0.f }, q[2] = { 0.f, 0.f };
    int rbase = r0 + quad * 4;
#pragma unroll
    for (int rr = 0; rr < 4; rr++) {
        int row = rbase + rr;
#pragma unroll
        for (int nt = 0; nt < 2; nt++) {
            float v = ahh[nt][rr] + ahl[nt][rr] * (1.0f / 1024.0f)
                    + alh[nt][rr] * (1.0f / 512.0f);
            int col = n0w + nt * 16 + l16;
            outT[row * HD + col] = v;
            s[nt] += v;
            q[nt] = fmaf(v, v, q[nt]);
        }
    }
#pragma unroll
    for (int nt = 0; nt < 2; nt++) {
        float ss = s[nt], qq = q[nt];
        ss += __shfl_xor(ss, 16); ss += __shfl_xor(ss, 32);
        qq += __shfl_xor(qq, 16); qq += __shfl_xor(qq, 32);
        if (lane < 16) {
            stat_add(&stat_out[rep + n0w + nt * 16 + lane], ss);
            stat_add(&stat_out[rep + 128 + n0w + nt * 16 + lane], qq);
        }
    }
}

// ---------- fp16-MFMA GEMM, 32-row tile, fp32 A, 3-term split ----------
template <bool BNRELU, bool OUTF16>
__global__ __launch_bounds__(256) void k_gemm(
    const float* __restrict__ A,
    const _Float16* __restrict__ Whi, const _Float16* __restrict__ Wlo,
    const i64* __restrict__ stat_in,
    const float* __restrict__ gamma, const float* __restrict__ beta,
    void* __restrict__ outv, _Float16* __restrict__ out1,
    i64* __restrict__ stat_out) {
    __shared__ __align__(16) _Float16 AsH[32 * AST];
    __shared__ __align__(16) _Float16 AsL[32 * AST];
    int tid  = threadIdx.x;
    int wave = tid >> 6, lane = tid & 63;
    int quad = lane >> 4, l16 = lane & 15;
    int r0   = blockIdx.x * 32;               // 625 blocks: no guards
    int n0w  = wave * 32;
    int rep  = (blockIdx.x & (NR - 1)) * 256;

    f16x8 bhi[2][4], blo[2][4];
#pragma unroll
    for (int nt = 0; nt < 2; nt++) {
        int n = n0w + nt * 16 + l16;
#pragma unroll
        for (int kq = 0; kq < 4; kq++) {
            int k = kq * 32 + quad * 8;
            bhi[nt][kq] = *(const f16x8*)&Whi[n * HD + k];
            blo[nt][kq] = *(const f16x8*)&Wlo[n * HD + k];
        }
    }

    {
        int c8 = (tid & 15) * 8;
        int nl = tid >> 4;
        float sc[8], sh[8];
        if (BNRELU) {
#pragma unroll
            for (int j = 0; j < 8; j++) {
                i64 S = 0, Q = 0;
#pragma unroll
                for (int r = 0; r < NR; r++) {
                    S += stat_in[r * 256 + c8 + j];
                    Q += stat_in[r * 256 + 128 + c8 + j];
                }
                float ssum = (float)((double)S * (1.0 / STS));
                float ssq  = (float)((double)Q * (1.0 / STS));
                float mu  = ssum * (1.0f / NN);
                float var = ssq * (1.0f / NN) - mu * mu;
                float a = gamma[c8 + j] * rsqrtf(var + BN_EPS);
                sc[j] = a;
                sh[j] = beta[c8 + j] - a * mu;
            }
        }
#pragma unroll
        for (int i = 0; i < 2; i++) {
            int r = i * 16 + nl;
            int row = r0 + r;
            float4 a0 = *(const float4*)&A[row * HD + c8];
            float4 a1 = *(const float4*)&A[row * HD + c8 + 4];
            float av8[8] = { a0.x, a0.y, a0.z, a0.w, a1.x, a1.y, a1.z, a1.w };
            f16x8 hh, ll;
#pragma unroll
            for (int j = 0; j < 8; j++) {
                float a = av8[j];
                if (BNRELU) a = fmaxf(fmaf(sc[j], a, sh[j]), 0.f);
                _Float16 h = (_Float16)a;
                hh[j] = h;
                ll[j] = (_Float16)((a - (float)h) * 512.0f);
            }
            *(f16x8*)&AsH[r * AST + c8] = hh;
            *(f16x8*)&AsL[r * AST + c8] = ll;
        }
    }
    __syncthreads();

    f32x4 ahh[2][2], ahl[2][2], alh[2][2];
#pragma unroll
    for (int mt = 0; mt < 2; mt++)
#pragma unroll
        for (int nt = 0; nt < 2; nt++)
#pragma unroll
            for (int e2 = 0; e2 < 4; e2++) {
                ahh[mt][nt][e2] = 0.f; ahl[mt][nt][e2] = 0.f; alh[mt][nt][e2] = 0.f;
            }

#pragma unroll
    for (int mt = 0; mt < 2; mt++) {
        int mrow = mt * 16 + l16;
#pragma unroll
        for (int kq = 0; kq < 4; kq++) {
            f16x8 ah = *(const f16x8*)&AsH[mrow * AST + kq * 32 + quad * 8];
            f16x8 al = *(const f16x8*)&AsL[mrow * AST + kq * 32 + quad * 8];
#pragma unroll
            for (int nt = 0; nt < 2; nt++) {
                ahh[mt][nt] = __builtin_amdgcn_mfma_f32_16x16x32_f16(ah, bhi[nt][kq], ahh[mt][nt], 0, 0, 0);
                ahl[mt][nt] = __builtin_amdgcn_mfma_f32_16x16x32_f16(ah, blo[nt][kq], ahl[mt][nt], 0, 0, 0);
                alh[mt][nt] = __builtin_amdgcn_mfma_f32_16x16x32_f16(al, bhi[nt][kq], alh[mt][nt], 0, 0, 0);
            }
        }
    }

    float s[2] = { 0.f, 0.f }, q[2] = { 0.f, 0.f };
#pragma unroll
    for (int mt = 0; mt < 2; mt++) {
        int rbase = r0 + mt * 16 + quad * 4;
#pragma unroll
        for (int rr = 0; rr < 4; rr++) {
            int row = rbase + rr;
#pragma unroll
            for (int nt = 0; nt < 2; nt++) {
                float v = ahh[mt][nt][rr] + ahl[mt][nt][rr] * (1.0f / 1024.0f)
                        + alh[mt][nt][rr] * (1.0f / 512.0f);
                int col = n0w + nt * 16 + l16;
                if (OUTF16) {
                    _Float16* dst = (col < 64) ? (_Float16*)outv : out1;
                    dst[row * 64 + (col & 63)] = (_Float16)v;
                } else {
                    ((float*)outv)[row * HD + col] = v;
                }
                s[nt] += v;
                q[nt] = fmaf(v, v, q[nt]);
            }
        }
    }
#pragma unroll
    for (int nt = 0; nt < 2; nt++) {
        float ss = s[nt], qq = q[nt];
        ss += __shfl_xor(ss, 16); ss += __shfl_xor(ss, 32);
        qq += __shfl_xor(qq, 16); qq += __shfl_xor(qq, 32);
        if (lane < 16) {
            stat_add(&stat_out[rep + n0w + nt * 16 + lane], ss);
            stat_add(&stat_out[rep + 128 + n0w + nt * 16 + lane], qq);
        }
    }
}

// ---------- pool + classifier (split fp16 u, inline BN) ----------
__global__ __launch_bounds__(256) void k_pool(
    const _Float16* __restrict__ u0, const _Float16* __restrict__ u1,
    const i64* __restrict__ stat_in,
    const float* __restrict__ gamma, const float* __restrict__ beta,
    const int* __restrict__ batch, const float* __restrict__ Wc,
    const float* __restrict__ bc, float* __restrict__ out) {
    __shared__ float part[2][HD];
    __shared__ float pooled[HD];
    __shared__ int range[2];
    int g = blockIdx.x;
    int tid = threadIdx.x;
    if (tid < 2) {
        int target = g + tid;
        int lo = 0, hi = NN;
        while (lo < hi) {
            int mid = (lo + hi) >> 1;
            if (batch[mid] < target) lo = mid + 1; else hi = mid;
        }
        range[tid] = lo;
    }
    __syncthreads();
    int start = range[0], end = range[1];
    int c    = tid & (HD - 1);
    int half = tid >> 7;
    const _Float16* uh = (c < 64) ? u0 : u1;
    int cin = c & 63;
    i64 S = 0, Q = 0;
#pragma unroll
    for (int r = 0; r < NR; r++) {
        S += stat_in[r * 256 + c];
        Q += stat_in[r * 256 + 128 + c];
    }
    float ssum = (float)((double)S * (1.0 / STS));
    float ssq  = (float)((double)Q * (1.0 / STS));
    float mu  = ssum * (1.0f / NN);
    float var = ssq * (1.0f / NN) - mu * mu;
    float sc = gamma[c] * rsqrtf(var + BN_EPS);
    float sh = beta[c] - sc * mu;
    float acc = 0.f;
    for (int n = start + half; n < end; n += 2)
        acc += fmaxf(fmaf(sc, (float)uh[n * 64 + cin], sh), 0.f);
    part[half][c] = acc;
    __syncthreads();
    if (tid < HD) {
        float inv = 1.0f / fmaxf((float)(end - start), 1.0f);
        pooled[tid] = (part[0][tid] + part[1][tid]) * inv;
    }
    __syncthreads();
    if (tid < NC) {
        float a = bc[tid];
        for (int k = 0; k < HD; k++)
            a = fmaf(pooled[k], Wc[k * NC + tid], a);
        out[g * NC + tid] = a;
    }
}

extern "C" void kernel_launch(void* const* d_in, const int* in_sizes, int n_in,
                              void* d_out, int out_size, void* d_ws, size_t ws_size,
                              hipStream_t stream) {
    const float* x      = (const float*)d_in[0];
    const int*   ei     = (const int*)d_in[1];
    const int*   batch  = (const int*)d_in[2];
    const float* enc_W  = (const float*)d_in[3];
    const float* enc_b  = (const float*)d_in[4];
    const float* W1     = (const float*)d_in[5];
    // d_in[6] = b1, d_in[10] = b2: cancel in the following BN (mean shift)
    const float* g1     = (const float*)d_in[7];
    const float* be1    = (const float*)d_in[8];
    const float* W2     = (const float*)d_in[9];
    const float* eps_g  = (const float*)d_in[11];
    const float* bn_g   = (const float*)d_in[12];
    const float* bn_b   = (const float*)d_in[13];
    const float* cls_W  = (const float*)d_in[14];
    const float* cls_b  = (const float*)d_in[15];
    float* out = (float*)d_out;

    _Float16* Wt    = (_Float16*)d_ws;                 // 12 x HD x HD fp16
    float* bufZ     = (float*)(Wt + 12 * HD * HD);     // NN*HD fp32 (wq lives here)
    float* bufT     = bufZ + NN * HD;                  // NN*HD fp32 (ag1 out)
    _Float16* bufU0 = (_Float16*)(bufT + NN * HD);     // NN*64 fp16 (u, ch 0-63)
    _Float16* bufU1 = bufU0 + NN * 64;                 // NN*64 fp16 (u, ch 64-127)
    int2* brec      = (int2*)(bufU1 + NN * 64);        // NB x BCAP records
    i64* stats      = (i64*)(brec + NB * BCAP);        // 6 units x NR x 256 (i64)
    i64* scal       = stats + 6 * NR * 256;            // 8 (i64)
    int* gcur       = (int*)(scal + 8);                // NB bucket cursors
    int* agbar      = gcur + NB;                       // 8 barrier counters
    float* pq       = (float*)(agbar + 8);             // 2*HD
    float* av       = pq + 2 * HD;                     // NN
    float* dv       = av + NN;                         // NN
    int* row_ptr    = (int*)(dv + NN);                 // NN+1
    int* csr_src    = row_ptr + NN + 1;                // NE
    _Float16* wq    = (_Float16*)bufZ;                 // NN*HD fp16 (5 MB)

    hipMemsetAsync(stats, 0,
                   6 * NR * 256 * sizeof(i64) + 8 * sizeof(i64)
                   + (NB + 8) * sizeof(int),
                   stream);

    dim3 b256(256);
    k_setup<<<549, b256, 0, stream>>>(enc_W, enc_b, W1, W2, ei, Wt, pq, brec, gcur);
    k_csr<<<NB, b256, 0, stream>>>(brec, gcur, x, eps_g, row_ptr, csr_src, av, dv, scal);

    const int gemm_blocks = NN / 32;                 // 625

#define STU(u) (stats + (u) * NR * 256)

    // ---- layer 0: rank-2 collapse (no enc, no aggr, no gemm1) ----
    k_gemmA<<<gemm_blocks, b256, 0, stream>>>(
        av, dv, pq, scal, g1, be1,
        Wt + 1 * HD * HD, Wt + 7 * HD * HD, bufU0, bufU1, STU(1));

    // ---- layers 1,2: fused vq+aggr+gemm1 (spin barrier), then gemm2 ----
    for (int l = 1; l < NL; l++) {
        _Float16* Whi1 = Wt + (2 * l) * HD * HD;
        _Float16* Wlo1 = Wt + (6 + 2 * l) * HD * HD;
        _Float16* Whi2 = Wt + (2 * l + 1) * HD * HD;
        _Float16* Wlo2 = Wt + (6 + 2 * l + 1) * HD * HD;
        k_ag1<<<AG1B, b256, 0, stream>>>(
            row_ptr, csr_src, bufU0, bufU1, STU(2 * l - 1),
            bn_g + (l - 1) * HD, bn_b + (l - 1) * HD, eps_g, l,
            Whi1, Wlo1, wq, bufT, STU(2 * l), agbar + (l - 1));
        k_gemm<true, true><<<gemm_blocks, b256, 0, stream>>>(
            bufT, Whi2, Wlo2, STU(2 * l), g1 + l * HD, be1 + l * HD,
            bufU0, bufU1, STU(2 * l + 1));
    }
    k_pool<<<NG, b256, 0, stream>>>(bufU0, bufU1, STU(5),
                                    bn_g + 2 * HD, bn_b + 2 * HD,
                                    batch, cls_W, cls_b, out);
}

// Round 12
// 280.312 us; speedup vs baseline: 2.2939x; 2.2939x over previous
//
#include <hip/hip_runtime.h>

#define NN 20000
#define NE 640000
#define HD 128
#define NL 3
#define NG 128
#define NC 2
#define BN_EPS 1e-5f
#define NR 4            // stat replicas (atomic spread)
#define AST 136
#define NB 157          // dst buckets (dst >> 7), 128 nodes each
#define BCAP 6144       // records per bucket (mean 4076, +32 sigma)

// Determinism scales. All cross-thread accumulation is either integer-exact
// or grid-quantized-exact float, so every call is bit-identical:
//  - WGRID (1/256): per-node BN-ReLU outputs quantized to the 2^-8 grid in
//    k_vq and stored as fp16 (every multiple of 2^-8 below 8.0 is fp16-exact;
//    >=8 rounds to a coarser fp16 grid which is still a 2^-8 multiple).
//    Aggregation sums of grid terms in f32 stay exact (|sum|*256 < 2^24)
//    => order-free AND partition-free (used by the half-list split).
//    This also makes csr_src ordering irrelevant to the output bits.
//  - SXS: layer-0 x sums in int32 (|x|<=5, deg<=70 -> < 2^31).
//  - STS/SCS: BN stats / layer-0 scalar moments in int64 fixed point.
// NOTE (r11 lesson): do NOT replace the k_vq->k_ag1 dispatch boundary with an
// in-kernel agent-scope spin barrier — acquire spins invalidate caches on
// CDNA and cost ~100x the dispatch boundary (643 us vs 281 us total).
#define WGRID 256.0f
#define SXS 65536.0f
#define STS 262144.0
#define SCS 1048576.0

typedef __attribute__((ext_vector_type(4))) float f32x4;
typedef __attribute__((ext_vector_type(8))) _Float16 f16x8;
typedef long long i64;

__device__ inline void stat_add(i64* p, float v) {
    atomicAdd((unsigned long long*)p, (unsigned long long)(i64)((double)v * STS));
}

// ---------- fused setup: weight fp16-split prep + p/q + edge bucketize ----------
// Bucketize stages records in LDS sorted by bucket, then streams them out:
// consecutive lanes write consecutive records whose destinations form
// contiguous runs per bucket -> ~8x fewer write transactions. [r9: +5 us]
__global__ void k_setup(const float* __restrict__ encW, const float* __restrict__ encb,
                        const float* __restrict__ W1, const float* __restrict__ W2,
                        const int* __restrict__ ei,
                        _Float16* __restrict__ Wt, float* __restrict__ pq,
                        int2* __restrict__ brec, int* __restrict__ gcur) {
    __shared__ int cnt[NB];
    __shared__ int base[NB];
    int b = blockIdx.x, tid = threadIdx.x;
    if (b < 48) {
        int t = b * 256 + tid;                 // 6*2048 = 12288
        if (t >= 6 * 2048) return;
        int mat = t >> 11;
        int rem = t & 2047;
        int n  = rem >> 4;
        int k0 = (rem & 15) * 8;
        int l  = mat >> 1;
        const float* src = (mat & 1) ? (W2 + l * HD * HD) : (W1 + l * HD * HD);
        _Float16* dhi = Wt + mat * HD * HD;
        _Float16* dlo = Wt + (6 + mat) * HD * HD;
        f16x8 hi, lo;
#pragma unroll
        for (int j = 0; j < 8; j++) {
            float w = src[(k0 + j) * HD + n];
            _Float16 hh = (_Float16)w;
            hi[j] = hh;
            lo[j] = (_Float16)((w - (float)hh) * 1024.0f);
        }
        *(f16x8*)&dhi[n * HD + k0] = hi;
        *(f16x8*)&dlo[n * HD + k0] = lo;
    } else if (b == 48) {
        if (tid < HD) {
            float ps = 0.f, qs = 0.f;
            for (int k = 0; k < HD; k++) {
                float w = W1[k * HD + tid];
                ps = fmaf(encW[k], w, ps);
                qs = fmaf(encb[k], w, qs);
            }
            pq[tid] = ps;
            pq[HD + tid] = qs;
        }
    } else {
        __shared__ int lscan[NB];              // inclusive local prefix
        __shared__ int cnt2[NB];
        __shared__ int2 st[1280];              // bucket-sorted staging
        int bb = b - 49;                       // 0..499, 1280 edges each (exact)
        for (int i = tid; i < NB; i += 256) { cnt[i] = 0; cnt2[i] = 0; }
        __syncthreads();
        int src[5], dst[5];
#pragma unroll
        for (int j = 0; j < 5; j++) {
            int e = bb * 1280 + j * 256 + tid;
            src[j] = ei[e];
            dst[j] = ei[NE + e];
            atomicAdd(&cnt[dst[j] >> 7], 1);
        }
        __syncthreads();
        // inclusive Hillis-Steele scan of cnt into lscan (NB <= 256)
        if (tid < NB) lscan[tid] = cnt[tid];
        __syncthreads();
        for (int off = 1; off < NB; off <<= 1) {
            int t = (tid < NB && tid >= off) ? lscan[tid - off] : 0;
            __syncthreads();
            if (tid < NB) lscan[tid] += t;
            __syncthreads();
        }
        // global reserve per bucket
        for (int i = tid; i < NB; i += 256)
            base[i] = atomicAdd(&gcur[i], cnt[i]);
        __syncthreads();
        // stage records sorted by bucket
#pragma unroll
        for (int j = 0; j < 5; j++) {
            int bk = dst[j] >> 7;
            int lpos = (lscan[bk] - cnt[bk]) + atomicAdd(&cnt2[bk], 1);
            st[lpos] = make_int2(src[j], dst[j]);
        }
        __syncthreads();
        // coalesced-run write-out
        for (int i = tid; i < 1280; i += 256) {
            int2 rc = st[i];
            int bk = rc.y >> 7;
            int excl = lscan[bk] - cnt[bk];
            brec[bk * BCAP + base[bk] + (i - excl)] = rc;
        }
    }
}

// ---------- CSR finalize + layer-0 scalar aggregation, per bucket ----------
// Single global pass; node-sorted in LDS; coalesced csr_src write-out.
__global__ void k_csr(const int2* __restrict__ brec, const int* __restrict__ gcur,
                      const float* __restrict__ x, const float* __restrict__ eps_gin,
                      int* __restrict__ row_ptr, int* __restrict__ csr_src,
                      float* __restrict__ av, float* __restrict__ dv,
                      i64* __restrict__ scal) {
    __shared__ int lc[128];
    __shared__ int sxi[128];
    __shared__ int pfx[128];
    __shared__ int sbase[4];
    __shared__ int cnt2[128];
    __shared__ int2 st[BCAP];                  // raw record staging (48 KB)
    __shared__ int  srt[BCAP];                 // node-sorted src ids (24 KB)
    int b = blockIdx.x, tid = threadIdx.x;
    if (tid < 128) { lc[tid] = 0; sxi[tid] = 0; cnt2[tid] = 0; }
    __syncthreads();
    int nrec = gcur[b];
    const int2* rec = brec + b * BCAP;
    // pass A: global->LDS copy + count + x-sum (int atomics, exact)
    for (int r = tid; r < nrec; r += 256) {
        int2 rc = rec[r];
        st[r] = rc;
        atomicAdd(&lc[rc.y & 127], 1);
        atomicAdd(&sxi[rc.y & 127], (int)rintf(x[rc.x] * SXS));
    }
    int v = (tid < b) ? gcur[tid] : 0;     // b <= 156 < 256
    v += __shfl_xor(v, 1);  v += __shfl_xor(v, 2);  v += __shfl_xor(v, 4);
    v += __shfl_xor(v, 8);  v += __shfl_xor(v, 16); v += __shfl_xor(v, 32);
    if ((tid & 63) == 0) sbase[tid >> 6] = v;
    __syncthreads();
    int base0 = sbase[0] + sbase[1] + sbase[2] + sbase[3];
    if (tid < 128) pfx[tid] = lc[tid];
    __syncthreads();
    for (int off = 1; off < 128; off <<= 1) {
        int t = (tid < 128 && tid >= off) ? pfx[tid - off] : 0;
        __syncthreads();
        if (tid < 128) pfx[tid] += t;
        __syncthreads();
    }
    if (tid < 128) {
        int node = b * 128 + tid;
        int e = base0 + pfx[tid] - lc[tid];   // exclusive
        if (node < NN) row_ptr[node] = e;
    }
    if (b == NB - 1 && tid == 0) row_ptr[NN] = NE;
    __syncthreads();
    // pass B: node-sort src ids (LDS -> LDS)
    for (int r = tid; r < nrec; r += 256) {
        int2 rc = st[r];
        int node = rc.y & 127;
        int lpos = (pfx[node] - lc[node]) + atomicAdd(&cnt2[node], 1);
        srt[lpos] = rc.x;
    }
    __syncthreads();
    // pass C: coalesced csr_src write-out
    for (int i = tid; i < nrec; i += 256)
        csr_src[base0 + i] = srt[i];
    __syncthreads();
    float a = 0.f, d = 0.f;
    if (tid < 128) {
        int node = b * 128 + tid;
        if (node < NN) {
            float e = 1.0f + eps_gin[0];
            float sxf = (float)sxi[tid] * (1.0f / SXS);
            a = fmaf(e, x[node], sxf);
            d = e + (float)lc[tid];
            av[node] = a;
            dv[node] = d;
        }
    }
    float vv[5] = { a, d, a * a, d * d, a * d };
#pragma unroll
    for (int j = 0; j < 5; j++) {
        float t = vv[j];
        t += __shfl_xor(t, 1);  t += __shfl_xor(t, 2);  t += __shfl_xor(t, 4);
        t += __shfl_xor(t, 8);  t += __shfl_xor(t, 16); t += __shfl_xor(t, 32);
        vv[j] = t;
    }
    if ((tid & 63) == 0 && tid < 128)
#pragma unroll
        for (int j = 0; j < 5; j++)
            atomicAdd((unsigned long long*)&scal[j],
                      (unsigned long long)(i64)((double)vv[j] * SCS));
}

// ---------- layer-0 GEMM2: rank-2 A, analytic BN, 3-term split, 32-row tile ----------
__global__ __launch_bounds__(256) void k_gemmA(
    const float* __restrict__ av, const float* __restrict__ dv,
    const float* __restrict__ pq, const i64* __restrict__ scal,
    const float* __restrict__ gamma, const float* __restrict__ beta,
    const _Float16* __restrict__ Whi, const _Float16* __restrict__ Wlo,
    _Float16* __restrict__ out0, _Float16* __restrict__ out1,
    i64* __restrict__ stat_out) {
    __shared__ __align__(16) _Float16 AsH[32 * AST];
    __shared__ __align__(16) _Float16 AsL[32 * AST];
    int tid  = threadIdx.x;
    int wave = tid >> 6, lane = tid & 63;
    int quad = lane >> 4, l16 = lane & 15;
    int r0   = blockIdx.x * 32;               // 625 blocks, no guards
    int n0w  = wave * 32;
    int rep  = (blockIdx.x & (NR - 1)) * 256;

    f16x8 bhi[2][4], blo[2][4];
#pragma unroll
    for (int nt = 0; nt < 2; nt++) {
        int n = n0w + nt * 16 + l16;
#pragma unroll
        for (int kq = 0; kq < 4; kq++) {
            int k = kq * 32 + quad * 8;
            bhi[nt][kq] = *(const f16x8*)&Whi[n * HD + k];
            blo[nt][kq] = *(const f16x8*)&Wlo[n * HD + k];
        }
    }

    {
        int c8 = (tid & 15) * 8;
        int nl = tid >> 4;
        float Sa  = (float)((double)scal[0] * (1.0 / SCS));
        float Sd  = (float)((double)scal[1] * (1.0 / SCS));
        float Saa = (float)((double)scal[2] * (1.0 / SCS));
        float Sdd = (float)((double)scal[3] * (1.0 / SCS));
        float Sad = (float)((double)scal[4] * (1.0 / SCS));
        float pj[8], qj[8], sc[8], sh[8];
#pragma unroll
        for (int j = 0; j < 8; j++) {
            float P = pq[c8 + j], Q = pq[HD + c8 + j];
            pj[j] = P; qj[j] = Q;
            float mu  = (Sa * P + Sd * Q) * (1.0f / NN);
            float ex2 = (Saa * P * P + 2.f * Sad * P * Q + Sdd * Q * Q) * (1.0f / NN);
            float var = ex2 - mu * mu;
            float g = gamma[c8 + j] * rsqrtf(var + BN_EPS);
            sc[j] = g;
            sh[j] = beta[c8 + j] - g * mu;
        }
#pragma unroll
        for (int i = 0; i < 2; i++) {
            int r = i * 16 + nl;
            int row = r0 + r;
            float a = av[row], d = dv[row];
            f16x8 hh, ll;
#pragma unroll
            for (int j = 0; j < 8; j++) {
                float t0 = fmaf(a, pj[j], d * qj[j]);
                float v = fmaxf(fmaf(sc[j], t0, sh[j]), 0.f);
                _Float16 h = (_Float16)v;
                hh[j] = h;
                ll[j] = (_Float16)((v - (float)h) * 512.0f);
            }
            *(f16x8*)&AsH[r * AST + c8] = hh;
            *(f16x8*)&AsL[r * AST + c8] = ll;
        }
    }
    __syncthreads();

    f32x4 ahh[2][2], ahl[2][2], alh[2][2];
#pragma unroll
    for (int mt = 0; mt < 2; mt++)
#pragma unroll
        for (int nt = 0; nt < 2; nt++)
#pragma unroll
            for (int e2 = 0; e2 < 4; e2++) {
                ahh[mt][nt][e2] = 0.f; ahl[mt][nt][e2] = 0.f; alh[mt][nt][e2] = 0.f;
            }

#pragma unroll
    for (int mt = 0; mt < 2; mt++) {
        int mrow = mt * 16 + l16;
#pragma unroll
        for (int kq = 0; kq < 4; kq++) {
            f16x8 ah = *(const f16x8*)&AsH[mrow * AST + kq * 32 + quad * 8];
            f16x8 al = *(const f16x8*)&AsL[mrow * AST + kq * 32 + quad * 8];
#pragma unroll
            for (int nt = 0; nt < 2; nt++) {
                ahh[mt][nt] = __builtin_amdgcn_mfma_f32_16x16x32_f16(ah, bhi[nt][kq], ahh[mt][nt], 0, 0, 0);
                ahl[mt][nt] = __builtin_amdgcn_mfma_f32_16x16x32_f16(ah, blo[nt][kq], ahl[mt][nt], 0, 0, 0);
                alh[mt][nt] = __builtin_amdgcn_mfma_f32_16x16x32_f16(al, bhi[nt][kq], alh[mt][nt], 0, 0, 0);
            }
        }
    }

    float s[2] = { 0.f, 0.f }, q[2] = { 0.f, 0.f };
#pragma unroll
    for (int mt = 0; mt < 2; mt++) {
        int rbase = r0 + mt * 16 + quad * 4;
#pragma unroll
        for (int rr = 0; rr < 4; rr++) {
            int row = rbase + rr;
#pragma unroll
            for (int nt = 0; nt < 2; nt++) {
                float v = ahh[mt][nt][rr] + ahl[mt][nt][rr] * (1.0f / 1024.0f)
                        + alh[mt][nt][rr] * (1.0f / 512.0f);
                int col = n0w + nt * 16 + l16;
                _Float16* dst = (col < 64) ? out0 : out1;
                dst[row * 64 + (col & 63)] = (_Float16)v;
                s[nt] += v;
                q[nt] = fmaf(v, v, q[nt]);
            }
        }
    }
#pragma unroll
    for (int nt = 0; nt < 2; nt++) {
        float ss = s[nt], qq = q[nt];
        ss += __shfl_xor(ss, 16); ss += __shfl_xor(ss, 32);
        qq += __shfl_xor(qq, 16); qq += __shfl_xor(qq, 32);
        if (lane < 16) {
            stat_add(&stat_out[rep + n0w + nt * 16 + lane], ss);
            stat_add(&stat_out[rep + 128 + n0w + nt * 16 + lane], qq);
        }
    }
}

// ---------- per-node BN+ReLU, 2^-8-grid-quantized, fp16: wq = rint(relu(bn(u))*256)/256 ----------
__global__ __launch_bounds__(256) void k_vq(
    const _Float16* __restrict__ u0, const _Float16* __restrict__ u1,
    const i64* __restrict__ stat_in,
    const float* __restrict__ gamma, const float* __restrict__ beta,
    _Float16* __restrict__ wq) {
    __shared__ float scs[HD], shs[HD];
    int tid = threadIdx.x;
    if (tid < HD) {
        i64 S = 0, Q = 0;
#pragma unroll
        for (int r = 0; r < NR; r++) {
            S += stat_in[r * 256 + tid];
            Q += stat_in[r * 256 + 128 + tid];
        }
        float ssum = (float)((double)S * (1.0 / STS));
        float ssq  = (float)((double)Q * (1.0 / STS));
        float mu  = ssum * (1.0f / NN);
        float var = ssq * (1.0f / NN) - mu * mu;
        float a = gamma[tid] * rsqrtf(var + BN_EPS);
        scs[tid] = a * WGRID;
        shs[tid] = (beta[tid] - a * mu) * WGRID;
    }
    __syncthreads();
    int i = blockIdx.x * 256 + tid;           // NN*16 = 320000 exact
    int n = i >> 4;
    int sub = i & 15;
    int half = sub >> 3;
    int c8in = (sub & 7) * 8;
    int c8 = half * 64 + c8in;
    const _Float16* u = half ? u1 : u0;
    f16x8 rv = *(const f16x8*)&u[n * 64 + c8in];
    f16x8 o;
#pragma unroll
    for (int j = 0; j < 8; j++)
        o[j] = (_Float16)(rintf(fmaxf(fmaf(scs[c8 + j], (float)rv[j], shs[c8 + j]), 0.f))
                          * (1.0f / WGRID));
    *(f16x8*)&wq[n * HD + c8] = o;
}

// ---------- FUSED aggregation + GEMM1, 16-row tile, 256 threads ----------
__global__ __launch_bounds__(256) void k_ag1(
    const int* __restrict__ row_ptr, const int* __restrict__ csr_src,
    const _Float16* __restrict__ wq,
    const float* __restrict__ eps_gin, int l,
    const _Float16* __restrict__ Whi, const _Float16* __restrict__ Wlo,
    float* __restrict__ outT, i64* __restrict__ stat_out) {
    __shared__ __align__(16) _Float16 AsH[16 * AST];
    __shared__ __align__(16) _Float16 AsL[16 * AST];
    int tid  = threadIdx.x;
    int wave = tid >> 6, lane = tid & 63;
    int quad = lane >> 4, l16 = lane & 15;
    int r0   = blockIdx.x * 16;               // 1250 blocks, no guards
    int n0w  = wave * 32;
    int rep  = (blockIdx.x & (NR - 1)) * 256;

    float e = 1.0f + eps_gin[l];
    {
        int node = tid >> 4;                  // 0..15
        int sub  = tid & 15;
        int hl   = sub >> 3;                  // which half of the edge list
        int c0   = (sub & 7) * 16;            // 16-channel base
        int n = r0 + node;
        int p0 = row_ptr[n], end0 = row_ptr[n + 1];
        int mid = p0 + ((end0 - p0) >> 1);
        float acc[16];
        if (hl == 0) {
            f16x8 s0 = *(const f16x8*)&wq[n * HD + c0];
            f16x8 s1 = *(const f16x8*)&wq[n * HD + c0 + 8];
#pragma unroll
            for (int j = 0; j < 8; j++) {
                acc[j]     = rintf(e * (float)s0[j] * WGRID) * (1.0f / WGRID);
                acc[8 + j] = rintf(e * (float)s1[j] * WGRID) * (1.0f / WGRID);
            }
        } else {
#pragma unroll
            for (int j = 0; j < 16; j++) acc[j] = 0.f;
        }
        int p   = hl ? mid : p0;
        int end = hl ? end0 : mid;
        for (; p + 3 < end; p += 4) {
            f16x8 ra[4], rb[4];
#pragma unroll
            for (int k = 0; k < 4; k++) {
                int s = csr_src[p + k];
                ra[k] = *(const f16x8*)&wq[s * HD + c0];
                rb[k] = *(const f16x8*)&wq[s * HD + c0 + 8];
            }
#pragma unroll
            for (int k = 0; k < 4; k++)
#pragma unroll
                for (int j = 0; j < 8; j++) {
                    acc[j]     += (float)ra[k][j];
                    acc[8 + j] += (float)rb[k][j];
                }
        }
        for (; p < end; p++) {
            int s = csr_src[p];
            f16x8 r0v = *(const f16x8*)&wq[s * HD + c0];
            f16x8 r1v = *(const f16x8*)&wq[s * HD + c0 + 8];
#pragma unroll
            for (int j = 0; j < 8; j++) {
                acc[j]     += (float)r0v[j];
                acc[8 + j] += (float)r1v[j];
            }
        }
        // combine the two half-list partials (exact grid -> order-free)
#pragma unroll
        for (int j = 0; j < 16; j++) acc[j] += __shfl_xor(acc[j], 8);
        if (hl == 0) {
            f16x8 hh0, ll0, hh1, ll1;
#pragma unroll
            for (int j = 0; j < 8; j++) {
                float v0 = acc[j];
                _Float16 h0 = (_Float16)v0;
                hh0[j] = h0;
                ll0[j] = (_Float16)((v0 - (float)h0) * 512.0f);
                float v1 = acc[8 + j];
                _Float16 h1 = (_Float16)v1;
                hh1[j] = h1;
                ll1[j] = (_Float16)((v1 - (float)h1) * 512.0f);
            }
            *(f16x8*)&AsH[node * AST + c0]     = hh0;
            *(f16x8*)&AsH[node * AST + c0 + 8] = hh1;
            *(f16x8*)&AsL[node * AST + c0]     = ll0;
            *(f16x8*)&AsL[node * AST + c0 + 8] = ll1;
        }
    }

    f16x8 bhi[2][4], blo[2][4];
#pragma unroll
    for (int nt = 0; nt < 2; nt++) {
        int n = n0w + nt * 16 + l16;
#pragma unroll
        for (int kq = 0; kq < 4; kq++) {
            int k = kq * 32 + quad * 8;
            bhi[nt][kq] = *(const f16x8*)&Whi[n * HD + k];
            blo[nt][kq] = *(const f16x8*)&Wlo[n * HD + k];
        }
    }
    __syncthreads();

    f32x4 ahh[2], ahl[2], alh[2];
#pragma unroll
    for (int nt = 0; nt < 2; nt++)
#pragma unroll
        for (int e2 = 0; e2 < 4; e2++) {
            ahh[nt][e2] = 0.f; ahl[nt][e2] = 0.f; alh[nt][e2] = 0.f;
        }

#pragma unroll
    for (int kq = 0; kq < 4; kq++) {
        f16x8 ah = *(const f16x8*)&AsH[l16 * AST + kq * 32 + quad * 8];
        f16x8 al = *(const f16x8*)&AsL[l16 * AST + kq * 32 + quad * 8];
#pragma unroll
        for (int nt = 0; nt < 2; nt++) {
            ahh[nt] = __builtin_amdgcn_mfma_f32_16x16x32_f16(ah, bhi[nt][kq], ahh[nt], 0, 0, 0);
            ahl[nt] = __builtin_amdgcn_mfma_f32_16x16x32_f16(ah, blo[nt][kq], ahl[nt], 0, 0, 0);
            alh[nt] = __builtin_amdgcn_mfma_f32_16x16x32_f16(al, bhi[nt][kq], alh[nt], 0, 0, 0);
        }
    }

    float s[2] = { 0.f, 0.f }, q[2] = { 0.f, 0.f };
    int rbase = r0 + quad * 4;
#pragma unroll
    for (int rr = 0; rr < 4; rr++) {
        int row = rbase + rr;
#pragma unroll
        for (int nt = 0; nt < 2; nt++) {
            float v = ahh[nt][rr] + ahl[nt][rr] * (1.0f / 1024.0f)
                    + alh[nt][rr] * (1.0f / 512.0f);
            int col = n0w + nt * 16 + l16;
            outT[row * HD + col] = v;
            s[nt] += v;
            q[nt] = fmaf(v, v, q[nt]);
        }
    }
#pragma unroll
    for (int nt = 0; nt < 2; nt++) {
        float ss = s[nt], qq = q[nt];
        ss += __shfl_xor(ss, 16); ss += __shfl_xor(ss, 32);
        qq += __shfl_xor(qq, 16); qq += __shfl_xor(qq, 32);
        if (lane < 16) {
            stat_add(&stat_out[rep + n0w + nt * 16 + lane], ss);
            stat_add(&stat_out[rep + 128 + n0w + nt * 16 + lane], qq);
        }
    }
}

// ---------- fp16-MFMA GEMM, 32-row tile, fp32 A, 3-term split ----------
template <bool BNRELU, bool OUTF16>
__global__ __launch_bounds__(256) void k_gemm(
    const float* __restrict__ A,
    const _Float16* __restrict__ Whi, const _Float16* __restrict__ Wlo,
    const i64* __restrict__ stat_in,
    const float* __restrict__ gamma, const float* __restrict__ beta,
    void* __restrict__ outv, _Float16* __restrict__ out1,
    i64* __restrict__ stat_out) {
    __shared__ __align__(16) _Float16 AsH[32 * AST];
    __shared__ __align__(16) _Float16 AsL[32 * AST];
    int tid  = threadIdx.x;
    int wave = tid >> 6, lane = tid & 63;
    int quad = lane >> 4, l16 = lane & 15;
    int r0   = blockIdx.x * 32;               // 625 blocks: no guards
    int n0w  = wave * 32;
    int rep  = (blockIdx.x & (NR - 1)) * 256;

    f16x8 bhi[2][4], blo[2][4];
#pragma unroll
    for (int nt = 0; nt < 2; nt++) {
        int n = n0w + nt * 16 + l16;
#pragma unroll
        for (int kq = 0; kq < 4; kq++) {
            int k = kq * 32 + quad * 8;
            bhi[nt][kq] = *(const f16x8*)&Whi[n * HD + k];
            blo[nt][kq] = *(const f16x8*)&Wlo[n * HD + k];
        }
    }

    {
        int c8 = (tid & 15) * 8;
        int nl = tid >> 4;
        float sc[8], sh[8];
        if (BNRELU) {
#pragma unroll
            for (int j = 0; j < 8; j++) {
                i64 S = 0, Q = 0;
#pragma unroll
                for (int r = 0; r < NR; r++) {
                    S += stat_in[r * 256 + c8 + j];
                    Q += stat_in[r * 256 + 128 + c8 + j];
                }
                float ssum = (float)((double)S * (1.0 / STS));
                float ssq  = (float)((double)Q * (1.0 / STS));
                float mu  = ssum * (1.0f / NN);
                float var = ssq * (1.0f / NN) - mu * mu;
                float a = gamma[c8 + j] * rsqrtf(var + BN_EPS);
                sc[j] = a;
                sh[j] = beta[c8 + j] - a * mu;
            }
        }
#pragma unroll
        for (int i = 0; i < 2; i++) {
            int r = i * 16 + nl;
            int row = r0 + r;
            float4 a0 = *(const float4*)&A[row * HD + c8];
            float4 a1 = *(const float4*)&A[row * HD + c8 + 4];
            float av8[8] = { a0.x, a0.y, a0.z, a0.w, a1.x, a1.y, a1.z, a1.w };
            f16x8 hh, ll;
#pragma unroll
            for (int j = 0; j < 8; j++) {
                float a = av8[j];
                if (BNRELU) a = fmaxf(fmaf(sc[j], a, sh[j]), 0.f);
                _Float16 h = (_Float16)a;
                hh[j] = h;
                ll[j] = (_Float16)((a - (float)h) * 512.0f);
            }
            *(f16x8*)&AsH[r * AST + c8] = hh;
            *(f16x8*)&AsL[r * AST + c8] = ll;
        }
    }
    __syncthreads();

    f32x4 ahh[2][2], ahl[2][2], alh[2][2];
#pragma unroll
    for (int mt = 0; mt < 2; mt++)
#pragma unroll
        for (int nt = 0; nt < 2; nt++)
#pragma unroll
            for (int e2 = 0; e2 < 4; e2++) {
                ahh[mt][nt][e2] = 0.f; ahl[mt][nt][e2] = 0.f; alh[mt][nt][e2] = 0.f;
            }

#pragma unroll
    for (int mt = 0; mt < 2; mt++) {
        int mrow = mt * 16 + l16;
#pragma unroll
        for (int kq = 0; kq < 4; kq++) {
            f16x8 ah = *(const f16x8*)&AsH[mrow * AST + kq * 32 + quad * 8];
            f16x8 al = *(const f16x8*)&AsL[mrow * AST + kq * 32 + quad * 8];
#pragma unroll
            for (int nt = 0; nt < 2; nt++) {
                ahh[mt][nt] = __builtin_amdgcn_mfma_f32_16x16x32_f16(ah, bhi[nt][kq], ahh[mt][nt], 0, 0, 0);
                ahl[mt][nt] = __builtin_amdgcn_mfma_f32_16x16x32_f16(ah, blo[nt][kq], ahl[mt][nt], 0, 0, 0);
                alh[mt][nt] = __builtin_amdgcn_mfma_f32_16x16x32_f16(al, bhi[nt][kq], alh[mt][nt], 0, 0, 0);
            }
        }
    }

    float s[2] = { 0.f, 0.f }, q[2] = { 0.f, 0.f };
#pragma unroll
    for (int mt = 0; mt < 2; mt++) {
        int rbase = r0 + mt * 16 + quad * 4;
#pragma unroll
        for (int rr = 0; rr < 4; rr++) {
            int row = rbase + rr;
#pragma unroll
            for (int nt = 0; nt < 2; nt++) {
                float v = ahh[mt][nt][rr] + ahl[mt][nt][rr] * (1.0f / 1024.0f)
                        + alh[mt][nt][rr] * (1.0f / 512.0f);
                int col = n0w + nt * 16 + l16;
                if (OUTF16) {
                    _Float16* dst = (col < 64) ? (_Float16*)outv : out1;
                    dst[row * 64 + (col & 63)] = (_Float16)v;
                } else {
                    ((float*)outv)[row * HD + col] = v;
                }
                s[nt] += v;
                q[nt] = fmaf(v, v, q[nt]);
            }
        }
    }
#pragma unroll
    for (int nt = 0; nt < 2; nt++) {
        float ss = s[nt], qq = q[nt];
        ss += __shfl_xor(ss, 16); ss += __shfl_xor(ss, 32);
        qq += __shfl_xor(qq, 16); qq += __shfl_xor(qq, 32);
        if (lane < 16) {
            stat_add(&stat_out[rep + n0w + nt * 16 + lane], ss);
            stat_add(&stat_out[rep + 128 + n0w + nt * 16 + lane], qq);
        }
    }
}

// ---------- pool + classifier (split fp16 u, inline BN) ----------
__global__ __launch_bounds__(256) void k_pool(
    const _Float16* __restrict__ u0, const _Float16* __restrict__ u1,
    const i64* __restrict__ stat_in,
    const float* __restrict__ gamma, const float* __restrict__ beta,
    const int* __restrict__ batch, const float* __restrict__ Wc,
    const float* __restrict__ bc, float* __restrict__ out) {
    __shared__ float part[2][HD];
    __shared__ float pooled[HD];
    __shared__ int range[2];
    int g = blockIdx.x;
    int tid = threadIdx.x;
    if (tid < 2) {
        int target = g + tid;
        int lo = 0, hi = NN;
        while (lo < hi) {
            int mid = (lo + hi) >> 1;
            if (batch[mid] < target) lo = mid + 1; else hi = mid;
        }
        range[tid] = lo;
    }
    __syncthreads();
    int start = range[0], end = range[1];
    int c    = tid & (HD - 1);
    int half = tid >> 7;
    const _Float16* uh = (c < 64) ? u0 : u1;
    int cin = c & 63;
    i64 S = 0, Q = 0;
#pragma unroll
    for (int r = 0; r < NR; r++) {
        S += stat_in[r * 256 + c];
        Q += stat_in[r * 256 + 128 + c];
    }
    float ssum = (float)((double)S * (1.0 / STS));
    float ssq  = (float)((double)Q * (1.0 / STS));
    float mu  = ssum * (1.0f / NN);
    float var = ssq * (1.0f / NN) - mu * mu;
    float sc = gamma[c] * rsqrtf(var + BN_EPS);
    float sh = beta[c] - sc * mu;
    float acc = 0.f;
    for (int n = start + half; n < end; n += 2)
        acc += fmaxf(fmaf(sc, (float)uh[n * 64 + cin], sh), 0.f);
    part[half][c] = acc;
    __syncthreads();
    if (tid < HD) {
        float inv = 1.0f / fmaxf((float)(end - start), 1.0f);
        pooled[tid] = (part[0][tid] + part[1][tid]) * inv;
    }
    __syncthreads();
    if (tid < NC) {
        float a = bc[tid];
        for (int k = 0; k < HD; k++)
            a = fmaf(pooled[k], Wc[k * NC + tid], a);
        out[g * NC + tid] = a;
    }
}

extern "C" void kernel_launch(void* const* d_in, const int* in_sizes, int n_in,
                              void* d_out, int out_size, void* d_ws, size_t ws_size,
                              hipStream_t stream) {
    const float* x      = (const float*)d_in[0];
    const int*   ei     = (const int*)d_in[1];
    const int*   batch  = (const int*)d_in[2];
    const float* enc_W  = (const float*)d_in[3];
    const float* enc_b  = (const float*)d_in[4];
    const float* W1     = (const float*)d_in[5];
    // d_in[6] = b1, d_in[10] = b2: cancel in the following BN (mean shift)
    const float* g1     = (const float*)d_in[7];
    const float* be1    = (const float*)d_in[8];
    const float* W2     = (const float*)d_in[9];
    const float* eps_g  = (const float*)d_in[11];
    const float* bn_g   = (const float*)d_in[12];
    const float* bn_b   = (const float*)d_in[13];
    const float* cls_W  = (const float*)d_in[14];
    const float* cls_b  = (const float*)d_in[15];
    float* out = (float*)d_out;

    _Float16* Wt    = (_Float16*)d_ws;                 // 12 x HD x HD fp16
    float* bufZ     = (float*)(Wt + 12 * HD * HD);     // NN*HD fp32 (wq lives here)
    float* bufT     = bufZ + NN * HD;                  // NN*HD fp32 (ag1 out)
    _Float16* bufU0 = (_Float16*)(bufT + NN * HD);     // NN*64 fp16 (u, ch 0-63)
    _Float16* bufU1 = bufU0 + NN * 64;                 // NN*64 fp16 (u, ch 64-127)
    int2* brec      = (int2*)(bufU1 + NN * 64);        // NB x BCAP records
    i64* stats      = (i64*)(brec + NB * BCAP);        // 6 units x NR x 256 (i64)
    i64* scal       = stats + 6 * NR * 256;            // 8 (i64)
    int* gcur       = (int*)(scal + 8);                // NB bucket cursors
    float* pq       = (float*)(gcur + NB);             // 2*HD
    float* av       = pq + 2 * HD;                     // NN
    float* dv       = av + NN;                         // NN
    int* row_ptr    = (int*)(dv + NN);                 // NN+1
    int* csr_src    = row_ptr + NN + 1;                // NE
    _Float16* wq    = (_Float16*)bufZ;                 // NN*HD fp16 (5 MB)

    hipMemsetAsync(stats, 0,
                   6 * NR * 256 * sizeof(i64) + 8 * sizeof(i64) + NB * sizeof(int),
                   stream);

    dim3 b256(256);
    k_setup<<<549, b256, 0, stream>>>(enc_W, enc_b, W1, W2, ei, Wt, pq, brec, gcur);
    k_csr<<<NB, b256, 0, stream>>>(brec, gcur, x, eps_g, row_ptr, csr_src, av, dv, scal);

    const int gemm_blocks = NN / 32;                 // 625
    const int vq_blocks   = NN * 16 / 256;           // 1250
    const int ag1_blocks  = NN / 16;                 // 1250

#define STU(u) (stats + (u) * NR * 256)

    // ---- layer 0: rank-2 collapse (no enc, no aggr, no gemm1) ----
    k_gemmA<<<gemm_blocks, b256, 0, stream>>>(
        av, dv, pq, scal, g1, be1,
        Wt + 1 * HD * HD, Wt + 7 * HD * HD, bufU0, bufU1, STU(1));

    // ---- layers 1,2: vq (grid-fp16 BN hoist), fused aggr+gemm1, gemm2 ----
    for (int l = 1; l < NL; l++) {
        _Float16* Whi1 = Wt + (2 * l) * HD * HD;
        _Float16* Wlo1 = Wt + (6 + 2 * l) * HD * HD;
        _Float16* Whi2 = Wt + (2 * l + 1) * HD * HD;
        _Float16* Wlo2 = Wt + (6 + 2 * l + 1) * HD * HD;
        k_vq<<<vq_blocks, b256, 0, stream>>>(
            bufU0, bufU1, STU(2 * l - 1),
            bn_g + (l - 1) * HD, bn_b + (l - 1) * HD, wq);
        k_ag1<<<ag1_blocks, b256, 0, stream>>>(
            row_ptr, csr_src, wq, eps_g, l,
            Whi1, Wlo1, bufT, STU(2 * l));
        k_gemm<true, true><<<gemm_blocks, b256, 0, stream>>>(
            bufT, Whi2, Wlo2, STU(2 * l), g1 + l * HD, be1 + l * HD,
            bufU0, bufU1, STU(2 * l + 1));
    }
    k_pool<<<NG, b256, 0, stream>>>(bufU0, bufU1, STU(5),
                                    bn_g + 2 * HD, bn_b + 2 * HD,
                                    batch, cls_W, cls_b, out);
}